// Round 8
// baseline (261.062 us; speedup 1.0000x reference)
//
#include <hip/hip_runtime.h>
#include <hip/hip_bf16.h>
#include <stdint.h>

// ---------- types ----------
typedef __bf16 bf16x8 __attribute__((ext_vector_type(8)));
typedef float  f32x4  __attribute__((ext_vector_type(4)));
typedef __hip_bfloat16 hbf16;

#define AS1 __attribute__((address_space(1)))
#define AS3 __attribute__((address_space(3)))

__device__ __forceinline__ void gload_lds16(const void* g, void* l) {
  __builtin_amdgcn_global_load_lds((const AS1 void*)g, (AS3 void*)l, 16, 0, 0);
}

__device__ __forceinline__ f32x4 mfma_bf16(bf16x8 a, bf16x8 b, f32x4 c) {
  return __builtin_amdgcn_mfma_f32_16x16x32_bf16(a, b, c, 0, 0, 0);
}

// Problem constants
// B=2, S=2048, HD=1024, NH=16, DH=64, chunks of 64 -> NC=32, BH = B*NH = 32

// ---------- fp32 -> bf16 conversion (WEIGHTS ONLY now; q/k/v folded into qkv)
__global__ __launch_bounds__(256) void convert_w(
    const float* __restrict__ wq, const float* __restrict__ wk,
    const float* __restrict__ wv, const float* __restrict__ wo,
    hbf16* __restrict__ dst)   // layout: wq | wk | wv | wo, 1M elems each
{
  const int i8 = (blockIdx.x * 256 + threadIdx.x) * 8;   // 0 .. 4M-8
  const float* src;
  int off;
  if      (i8 < (1 << 20)) { src = wq; off = i8; }
  else if (i8 < (2 << 20)) { src = wk; off = i8 - (1 << 20); }
  else if (i8 < (3 << 20)) { src = wv; off = i8 - (2 << 20); }
  else                     { src = wo; off = i8 - (3 << 20); }
  const float4 a = *(const float4*)(src + off);
  const float4 b = *(const float4*)(src + off + 4);
  hbf16 h[8];
  h[0] = __float2bfloat16(a.x); h[1] = __float2bfloat16(a.y);
  h[2] = __float2bfloat16(a.z); h[3] = __float2bfloat16(a.w);
  h[4] = __float2bfloat16(b.x); h[5] = __float2bfloat16(b.y);
  h[6] = __float2bfloat16(b.z); h[7] = __float2bfloat16(b.w);
  *(uint4*)(dst + i8) = *(uint4*)h;
}

// XCD-aware remap (grid (8,32): x-major dispatch -> XCD = blockIdx.x)
__device__ __forceinline__ void xcd_remap(int& bx, int& by) {
  const int X = blockIdx.x, Y = blockIdx.y;
  by = X * 4 + (Y & 3);
  bx = Y >> 2;
}

// ---------- QKV projection GEMM (fp32 A in-loop converted) + phi + epilogue --
// C = A32(4096x1024 fp32) * W(1024x1024 bf16)^T. 128x128 tile, 2-phase core.
// A path: reg-staged (8x float4 issue-early -> cvt+ds_write late, T14 split),
// swizzled ds_write dest. B path: proven global_load_lds w/ pre-swizzled src.
// grid (8, 32, 3): z = {q,k,v}.
__global__ __launch_bounds__(256, 3) void qkv_gemm(
    const float* __restrict__ qin, const float* __restrict__ kin, const float* __restrict__ vin,
    const hbf16* __restrict__ wq, const hbf16* __restrict__ wk, const hbf16* __restrict__ wv,
    const float* __restrict__ bq, const float* __restrict__ bk, const float* __restrict__ bv,
    hbf16* __restrict__ q_phi, hbf16* __restrict__ k_phi,
    hbf16* __restrict__ kphiT, hbf16* __restrict__ vT)
{
  const int z = blockIdx.z;
  const float* A32  = (z == 0) ? qin : (z == 1) ? kin : vin;
  const hbf16* W    = (z == 0) ? wq  : (z == 1) ? wk  : wv;
  const float* bias = (z == 0) ? bq  : (z == 1) ? bk  : bv;

  int bx, by;
  xcd_remap(bx, by);

  __shared__ hbf16 smem[2 * 128 * 64];   // 32KB: sA | sB, reused by epilogue
  hbf16* sA = smem;
  hbf16* sB = smem + 128 * 64;

  const int tid  = threadIdx.x;
  const int lane = tid & 63;
  const int wid  = tid >> 6;
  const int wm = wid >> 1, wn = wid & 1;
  const int l15 = lane & 15, l4 = lane >> 4;
  const int K = 1024;

  auto STAGEB = [&](int kt) {
    const int k0 = kt * 64;
    #pragma unroll
    for (int j = 0; j < 4; ++j) {
      const int o   = (j * 256 + tid) * 16;
      const int row = o >> 7;
      const int csw = (o & 127) ^ ((row & 7) << 4);
      gload_lds16((const char*)W + ((size_t)(bx * 128 + row) * K + k0) * 2 + csw,
                  (char*)sB + o);
    }
  };
  // issue 8 fp32 loads for A tile (kt) into regs (coalesced 32B/thread/j)
  auto LOADA = [&](int kt, float4 (&av)[4][2]) {
    #pragma unroll
    for (int j = 0; j < 4; ++j) {
      const int o   = (j * 256 + tid) * 16;    // byte offset in bf16 tile
      const int row = o >> 7;                  // 0..127
      const int col = (o & 127) >> 1;          // bf16/fp32 element col, 8-aligned
      const float4* src =
          (const float4*)&A32[((size_t)(by * 128 + row)) * K + kt * 64 + col];
      av[j][0] = src[0];
      av[j][1] = src[1];
    }
  };
  // cvt + swizzled ds_write of the A tile (reg-staged => dest swizzle is free)
  auto WRITEA = [&](float4 (&av)[4][2]) {
    #pragma unroll
    for (int j = 0; j < 4; ++j) {
      const int o   = (j * 256 + tid) * 16;
      const int row = o >> 7;
      const int osw = (o & ~127) | ((o & 127) ^ ((row & 7) << 4));
      const float* f = (const float*)av[j];
      hbf16 h[8];
      #pragma unroll
      for (int i = 0; i < 8; ++i) h[i] = __float2bfloat16(f[i]);
      *(uint4*)((char*)sA + osw) = *(uint4*)h;
    }
  };

  f32x4 acc[4][4] = {};
  float4 av[4][2];

  // prologue: stage tile 0 (B async; A load->cvt->write)
  STAGEB(0);
  LOADA(0, av);
  WRITEA(av);                 // compiler inserts the vmcnt wait before the cvts

  for (int kt = 0; kt < 16; ++kt) {
    __syncthreads();          // publishes tile kt (drains lgkm ds_writes + vm gloads)
    bf16x8 af[2][4], bfr[2][4];
    #pragma unroll
    for (int kk = 0; kk < 2; ++kk) {
      #pragma unroll
      for (int m = 0; m < 4; ++m) {
        const int row = wm * 64 + m * 16 + l15;
        const int col = (kk * 64 + l4 * 16) ^ ((row & 7) << 4);
        af[kk][m] = *(const bf16x8*)((const char*)sA + row * 128 + col);
      }
      #pragma unroll
      for (int n = 0; n < 4; ++n) {
        const int row = wn * 64 + n * 16 + l15;
        const int col = (kk * 64 + l4 * 16) ^ ((row & 7) << 4);
        bfr[kk][n] = *(const bf16x8*)((const char*)sB + row * 128 + col);
      }
    }
    __syncthreads();          // all frags in regs; LDS reusable
    if (kt < 15) {
      STAGEB(kt + 1);         // async B -> LDS, flies over MFMAs
      LOADA(kt + 1, av);      // A fp32 -> regs, flies over MFMAs
    }
    __builtin_amdgcn_sched_barrier(0);   // loads stay issued before MFMA
    #pragma unroll
    for (int kk = 0; kk < 2; ++kk)
      #pragma unroll
      for (int m = 0; m < 4; ++m)
        #pragma unroll
        for (int n = 0; n < 4; ++n)
          acc[m][n] = mfma_bf16(af[kk][m], bfr[kk][n], acc[m][n]);
    __builtin_amdgcn_sched_barrier(0);   // cvt/ds_write stay AFTER MFMA (T14)
    if (kt < 15) WRITEA(av);
  }

  // ---- epilogue: bias + phi + LDS-repacked coalesced stores (R6, proven) ----
  const int b = by >> 4;   // 128-row tile never crosses the batch boundary
  float bs[4];
  #pragma unroll
  for (int n = 0; n < 4; ++n) bs[n] = bias[bx * 128 + wn * 64 + n * 16 + l15];

  auto finish = [&](float v) -> float {
    return (z < 2) ? ((v > 0.f) ? (v + 1.f) : __expf(v)) : v;   // phi = elu+1
  };

  if (z < 2) {
    #pragma unroll
    for (int n = 0; n < 4; ++n) {
      const int col = wn * 64 + n * 16 + l15;
      #pragma unroll
      for (int m = 0; m < 4; ++m) {
        #pragma unroll
        for (int j = 0; j < 4; ++j) {
          const int row = wm * 64 + m * 16 + l4 * 4 + j;
          smem[row * 128 + (col ^ ((row & 7) << 3))] =
              __float2bfloat16(finish(acc[m][n][j] + bs[n]));
        }
      }
    }
    __syncthreads();
    hbf16* dst = (z == 0) ? q_phi : k_phi;
    #pragma unroll
    for (int it = 0; it < 8; ++it) {
      const int sgi = it * 256 + tid;          // 0..2047
      const int sl = sgi >> 4, seg = sgi & 15;
      const uint4 vv = *(const uint4*)&smem[sl * 128 + ((seg * 8) ^ ((sl & 7) << 3))];
      const int gnb = bx * 128 + seg * 8;
      const int h = gnb >> 6, dd = gnb & 63;
      const int s = (by * 128 + sl) & 2047;
      *(uint4*)&dst[(((size_t)(b * 16 + h)) * 2048 + s) * 64 + dd] = vv;
    }
  }
  if (z >= 1) {
    if (z == 1) __syncthreads();               // LDS reuse between passes
    #pragma unroll
    for (int n = 0; n < 4; ++n) {
      const int gnl = wn * 64 + n * 16 + l15;
      const int x = (gnl & 7) << 3;
      #pragma unroll
      for (int m = 0; m < 4; ++m) {
        const int s0 = wm * 64 + m * 16 + l4 * 4;
        hbf16 pk[4];
        #pragma unroll
        for (int j = 0; j < 4; ++j)
          pk[j] = __float2bfloat16(finish(acc[m][n][j] + bs[n]));
        *(ushort4*)&smem[gnl * 128 + (s0 ^ x)] = *(ushort4*)pk;
      }
    }
    __syncthreads();
    hbf16* dst = (z == 1) ? kphiT : vT;
    #pragma unroll
    for (int it = 0; it < 8; ++it) {
      const int sgi = it * 256 + tid;          // 0..2047
      const int gn = sgi >> 4, sseg = sgi & 15;
      const uint4 vv = *(const uint4*)&smem[gn * 128 + ((sseg * 8) ^ ((gn & 7) << 3))];
      const int gnb = bx * 128 + gn;
      const int h = gnb >> 6, dd = gnb & 63;
      const int sg = by * 128 + sseg * 8;
      const int c = (sg & 2047) >> 6, sin = sg & 63;
      *(uint4*)&dst[(((size_t)(b * 16 + h)) * 32 + c) * 4096 + dd * 64 + sin] = vv;
    }
  }
}

// ---------- per-chunk KV^T_ext sums: [80][64] fp32 per (bh, chunk) ----------
__global__ __launch_bounds__(256) void chunk_sums(
    const hbf16* __restrict__ kphiT, const hbf16* __restrict__ vT,
    float* __restrict__ sums)
{
  const int c = blockIdx.x, bh = blockIdx.y;
  const int tid = threadIdx.x, lane = tid & 63, w = tid >> 6;
  const int l15 = lane & 15, l4 = lane >> 4;
  const size_t tbase = ((size_t)bh * 32 + c) * 4096;

  f32x4 acc[5] = {};
  #pragma unroll
  for (int kk = 0; kk < 2; ++kk) {
    const bf16x8 bfr = *(const bf16x8*)&kphiT[tbase + (w * 16 + l15) * 64 + l4 * 8 + kk * 32];
    #pragma unroll
    for (int mj = 0; mj < 5; ++mj) {
      bf16x8 af;
      if (mj < 4) {
        af = *(const bf16x8*)&vT[tbase + (mj * 16 + l15) * 64 + l4 * 8 + kk * 32];
      } else {
        const __bf16 e = (l15 == 0) ? (__bf16)1.0f : (__bf16)0.0f;
        #pragma unroll
        for (int i = 0; i < 8; ++i) af[i] = e;
      }
      acc[mj] = mfma_bf16(af, bfr, acc[mj]);
    }
  }
  float* outp = sums + ((size_t)bh * 32 + c) * 5120;
  #pragma unroll
  for (int mj = 0; mj < 5; ++mj) {
    #pragma unroll
    for (int j = 0; j < 4; ++j) {
      outp[(mj * 16 + l4 * 4 + j) * 64 + w * 16 + l15] = acc[mj][j];
    }
  }
}

// ---------- exclusive prefix scan over chunks, output bf16 ----------
__global__ __launch_bounds__(256) void chunk_scan(
    const float* __restrict__ sums, hbf16* __restrict__ pre)
{
  const int elem = blockIdx.x * 256 + threadIdx.x;   // 0..5119
  const int bh = blockIdx.y;
  const size_t base = (size_t)bh * 32 * 5120 + elem;
  float v[32];
  #pragma unroll
  for (int c = 0; c < 32; ++c) v[c] = sums[base + (size_t)c * 5120];
  float run = 0.f;
  #pragma unroll
  for (int c = 0; c < 32; ++c) {
    pre[base + (size_t)c * 5120] = __float2bfloat16(run);
    run += v[c];
  }
}

// ---------- per-chunk attention: intra (masked) + inter (prefix) ----------
__global__ __launch_bounds__(256) void attn_chunk(
    const hbf16* __restrict__ q_phi, const hbf16* __restrict__ k_phi,
    const hbf16* __restrict__ vT, const hbf16* __restrict__ pre,
    hbf16* __restrict__ attn)
{
  const int c = blockIdx.x, bh = blockIdx.y;
  const int tid = threadIdx.x, lane = tid & 63, w = tid >> 6;
  const int l15 = lane & 15, l4 = lane >> 4;
  __shared__ hbf16 sS[4 * 16 * 64];   // scores, then reused as 64x64 out tile

  const size_t qbase = ((size_t)bh * 2048 + c * 64) * 64;
  const size_t tbase = ((size_t)bh * 32 + c) * 4096;
  const size_t pbase = ((size_t)bh * 32 + c) * 5120;

  bf16x8 aq[2];
  #pragma unroll
  for (int kk = 0; kk < 2; ++kk)
    aq[kk] = *(const bf16x8*)&q_phi[qbase + (w * 16 + l15) * 64 + l4 * 8 + kk * 32];

  f32x4 accS[4] = {};
  #pragma unroll
  for (int kk = 0; kk < 2; ++kk) {
    #pragma unroll
    for (int ni = 0; ni < 4; ++ni) {
      const bf16x8 bk = *(const bf16x8*)&k_phi[qbase + (ni * 16 + l15) * 64 + l4 * 8 + kk * 32];
      accS[ni] = mfma_bf16(aq[kk], bk, accS[ni]);
    }
  }
  #pragma unroll
  for (int ni = 0; ni < 4; ++ni) {
    #pragma unroll
    for (int j = 0; j < 4; ++j) {
      const int r  = l4 * 4 + j;
      const int cc = ni * 16 + l15;
      const float v = (cc <= w * 16 + r) ? accS[ni][j] : 0.f;
      sS[w * 1024 + r * 64 + (cc ^ ((r & 7) << 3))] = __float2bfloat16(v);
    }
  }
  // (wave-local LDS use: no barrier needed)

  f32x4 accN[5] = {};
  #pragma unroll
  for (int kk = 0; kk < 2; ++kk) {
    const bf16x8 aS = *(const bf16x8*)&sS[w * 1024 + l15 * 64 +
                                          ((l4 * 8 + kk * 32) ^ ((l15 & 7) << 3))];
    #pragma unroll
    for (int ni = 0; ni < 5; ++ni) {
      bf16x8 bv;
      if (ni < 4) {
        bv = *(const bf16x8*)&vT[tbase + (ni * 16 + l15) * 64 + l4 * 8 + kk * 32];
      } else {
        const __bf16 e = (l15 == 0) ? (__bf16)1.0f : (__bf16)0.0f;
        #pragma unroll
        for (int i = 0; i < 8; ++i) bv[i] = e;
      }
      accN[ni] = mfma_bf16(aS, bv, accN[ni]);
    }
  }
  #pragma unroll
  for (int kk = 0; kk < 2; ++kk) {
    #pragma unroll
    for (int ni = 0; ni < 5; ++ni) {
      const bf16x8 bp = *(const bf16x8*)&pre[pbase + (ni * 16 + l15) * 64 + l4 * 8 + kk * 32];
      accN[ni] = mfma_bf16(aq[kk], bp, accN[ni]);
    }
  }
  // divide + LDS repack + coalesced dump
  const int b = bh >> 4, h = bh & 15;
  #pragma unroll
  for (int j = 0; j < 4; ++j) {
    const float den = __shfl(accN[4][j], lane & 48);
    const float inv = 1.f / (den + 1e-6f);
    const int sl = w * 16 + l4 * 4 + j;
    #pragma unroll
    for (int ni = 0; ni < 4; ++ni) {
      sS[sl * 64 + ((ni * 16 + l15) ^ ((sl & 7) << 3))] =
          __float2bfloat16(accN[ni][j] * inv);
    }
  }
  __syncthreads();
  #pragma unroll
  for (int it = 0; it < 2; ++it) {
    const int sgi = it * 256 + tid;            // 0..511
    const int sl = sgi >> 3, seg = sgi & 7;
    const uint4 vv = *(const uint4*)&sS[sl * 64 + ((seg * 8) ^ ((sl & 7) << 3))];
    *(uint4*)&attn[((size_t)b * 2048 + c * 64 + sl) * 1024 + h * 64 + seg * 8] = vv;
  }
}

// ---------- output projection GEMM: 64x128 2-phase core, 512 blocks ----------
__global__ __launch_bounds__(256, 3) void out_gemm(
    const hbf16* __restrict__ attn, const hbf16* __restrict__ wo,
    const float* __restrict__ bo, float* __restrict__ out)
{
  // grid (8, 64): x-major dispatch -> XCD = blockIdx.x (512 % 8 == 0).
  const int X = blockIdx.x, Y = blockIdx.y;
  const int by = X * 8 + (Y & 7);   // 0..63
  const int bx = Y >> 3;            // 0..7

  __shared__ hbf16 sA[64 * 64];     // 8KB
  __shared__ hbf16 sB[128 * 64];    // 16KB
  const int tid  = threadIdx.x;
  const int lane = tid & 63;
  const int wid  = tid >> 6;
  const int l15 = lane & 15, l4 = lane >> 4;
  const int K = 1024;

  auto STAGE = [&](int kt) {
    const int k0 = kt * 64;
    #pragma unroll
    for (int j = 0; j < 2; ++j) {               // A tile 64x64
      const int o   = (j * 256 + tid) * 16;
      const int row = o >> 7;
      const int csw = (o & 127) ^ ((row & 7) << 4);
      gload_lds16((const char*)attn + ((size_t)(by * 64 + row) * K + k0) * 2 + csw,
                  (char*)sA + o);
    }
    #pragma unroll
    for (int j = 0; j < 4; ++j) {               // B tile 128x64
      const int o   = (j * 256 + tid) * 16;
      const int row = o >> 7;
      const int csw = (o & 127) ^ ((row & 7) << 4);
      gload_lds16((const char*)wo + ((size_t)(bx * 128 + row) * K + k0) * 2 + csw,
                  (char*)sB + o);
    }
  };

  f32x4 acc[4][2] = {};
  STAGE(0);
  for (int kt = 0; kt < 16; ++kt) {
    __syncthreads();
    bf16x8 af[2][4], bfr[2][2];
    #pragma unroll
    for (int kk = 0; kk < 2; ++kk) {
      #pragma unroll
      for (int m = 0; m < 4; ++m) {
        const int row = m * 16 + l15;
        const int col = (kk * 64 + l4 * 16) ^ ((row & 7) << 4);
        af[kk][m] = *(const bf16x8*)((const char*)sA + row * 128 + col);
      }
      #pragma unroll
      for (int n = 0; n < 2; ++n) {
        const int row = wid * 32 + n * 16 + l15;
        const int col = (kk * 64 + l4 * 16) ^ ((row & 7) << 4);
        bfr[kk][n] = *(const bf16x8*)((const char*)sB + row * 128 + col);
      }
    }
    __syncthreads();
    if (kt < 15) STAGE(kt + 1);
    __builtin_amdgcn_sched_barrier(0);
    #pragma unroll
    for (int kk = 0; kk < 2; ++kk)
      #pragma unroll
      for (int m = 0; m < 4; ++m)
        #pragma unroll
        for (int n = 0; n < 2; ++n)
          acc[m][n] = mfma_bf16(af[kk][m], bfr[kk][n], acc[m][n]);
  }

  #pragma unroll
  for (int n = 0; n < 2; ++n) {
    const int gn = bx * 128 + wid * 32 + n * 16 + l15;
    const float bs = bo[gn];
    #pragma unroll
    for (int m = 0; m < 4; ++m) {
      #pragma unroll
      for (int j = 0; j < 4; ++j) {
        const int gm = by * 64 + m * 16 + l4 * 4 + j;
        out[(size_t)gm * 1024 + gn] = acc[m][n][j] + bs;   // fp32, 64B lines
      }
    }
  }
}

// ---------- launch ----------
extern "C" void kernel_launch(void* const* d_in, const int* in_sizes, int n_in,
                              void* d_out, int out_size, void* d_ws, size_t ws_size,
                              hipStream_t stream) {
  const float* q  = (const float*)d_in[0];
  const float* k  = (const float*)d_in[1];
  const float* v  = (const float*)d_in[2];
  const float* Wq = (const float*)d_in[3];
  const float* bq = (const float*)d_in[4];
  const float* Wk = (const float*)d_in[5];
  const float* bk = (const float*)d_in[6];
  const float* Wv = (const float*)d_in[7];
  const float* bv = (const float*)d_in[8];
  const float* Wo = (const float*)d_in[9];
  const float* bo = (const float*)d_in[10];

  char* ws = (char*)d_ws;
  const size_t MB = (size_t)1 << 20;
  hbf16* wqb  = (hbf16*)(ws + 24 * MB);
  hbf16* wkb  = (hbf16*)(ws + 26 * MB);
  hbf16* wvb  = (hbf16*)(ws + 28 * MB);
  hbf16* wob  = (hbf16*)(ws + 30 * MB);
  hbf16* qphi = (hbf16*)(ws + 32 * MB);
  hbf16* kphi = (hbf16*)(ws + 40 * MB);
  hbf16* kphT = (hbf16*)(ws + 48 * MB);
  hbf16* vTb  = (hbf16*)(ws + 56 * MB);
  hbf16* attn = (hbf16*)(ws + 64 * MB);
  float* sums = (float*)(ws + 72 * MB);   // 20 MiB
  hbf16* pre  = (hbf16*)(ws + 92 * MB);

  convert_w<<<2048, 256, 0, stream>>>(Wq, Wk, Wv, Wo, wqb);  // wqb..wob contiguous
  qkv_gemm<<<dim3(8, 32, 3), 256, 0, stream>>>(q, k, v, wqb, wkb, wvb,
                                               bq, bk, bv, qphi, kphi, kphT, vTb);
  chunk_sums<<<dim3(32, 32), 256, 0, stream>>>(kphT, vTb, sums);
  chunk_scan<<<dim3(20, 32), 256, 0, stream>>>(sums, pre);
  attn_chunk<<<dim3(32, 32), 256, 0, stream>>>(qphi, kphi, vTb, pre, attn);
  out_gemm<<<dim3(8, 64), 256, 0, stream>>>(attn, wob, bo, (float*)d_out);
}

// Round 9
// 190.143 us; speedup vs baseline: 1.3730x; 1.3730x over previous
//
#include <hip/hip_runtime.h>
#include <hip/hip_bf16.h>
#include <stdint.h>

// ---------- types ----------
typedef __bf16 bf16x8 __attribute__((ext_vector_type(8)));
typedef float  f32x4  __attribute__((ext_vector_type(4)));
typedef __hip_bfloat16 hbf16;

#define AS1 __attribute__((address_space(1)))
#define AS3 __attribute__((address_space(3)))

__device__ __forceinline__ void gload_lds16(const void* g, void* l) {
  __builtin_amdgcn_global_load_lds((const AS1 void*)g, (AS3 void*)l, 16, 0, 0);
}

__device__ __forceinline__ f32x4 mfma_bf16(bf16x8 a, bf16x8 b, f32x4 c) {
  return __builtin_amdgcn_mfma_f32_16x16x32_bf16(a, b, c, 0, 0, 0);
}

// Problem constants
// B=2, S=2048, HD=1024, NH=16, DH=64, chunks of 64 -> NC=32, BH = B*NH = 32

// ---------- fp32 -> bf16 conversion (inputs + weights) ----------
__global__ __launch_bounds__(256) void convert_all(
    const float* __restrict__ q, const float* __restrict__ k, const float* __restrict__ v,
    const float* __restrict__ wq, const float* __restrict__ wk,
    const float* __restrict__ wv, const float* __restrict__ wo,
    hbf16* __restrict__ dst)
{
  const int i8 = (blockIdx.x * 256 + threadIdx.x) * 8;
  const float* src;
  int off;
  if      (i8 < (4  << 20)) { src = q;  off = i8; }
  else if (i8 < (8  << 20)) { src = k;  off = i8 - (4  << 20); }
  else if (i8 < (12 << 20)) { src = v;  off = i8 - (8  << 20); }
  else if (i8 < (13 << 20)) { src = wq; off = i8 - (12 << 20); }
  else if (i8 < (14 << 20)) { src = wk; off = i8 - (13 << 20); }
  else if (i8 < (15 << 20)) { src = wv; off = i8 - (14 << 20); }
  else                      { src = wo; off = i8 - (15 << 20); }
  const float4 a = *(const float4*)(src + off);
  const float4 b = *(const float4*)(src + off + 4);
  hbf16 h[8];
  h[0] = __float2bfloat16(a.x); h[1] = __float2bfloat16(a.y);
  h[2] = __float2bfloat16(a.z); h[3] = __float2bfloat16(a.w);
  h[4] = __float2bfloat16(b.x); h[5] = __float2bfloat16(b.y);
  h[6] = __float2bfloat16(b.z); h[7] = __float2bfloat16(b.w);
  *(uint4*)(dst + i8) = *(uint4*)h;
}

// ---------- 2-phase 128x128 GEMM core (proven R2): C = A*B^T, K=1024 ----------
// LDS tiles [128][64] bf16, XOR swizzle byte^=((row&7)<<4) via pre-swizzled
// global src (linear gload_lds dest) + swizzled ds_read.
__device__ __forceinline__ void gemm_core_128(
    const hbf16* __restrict__ A, const hbf16* __restrict__ Bw,
    int by, int bx, hbf16* sA, hbf16* sB, f32x4 (&acc)[4][4])
{
  const int tid  = threadIdx.x;
  const int lane = tid & 63;
  const int wid  = tid >> 6;
  const int wm = wid >> 1, wn = wid & 1;
  const int l15 = lane & 15, l4 = lane >> 4;
  const int K = 1024;

  auto STAGE = [&](int kt) {
    const int k0 = kt * 64;
    #pragma unroll
    for (int j = 0; j < 4; ++j) {
      const int o   = (j * 256 + tid) * 16;
      const int row = o >> 7;
      const int csw = (o & 127) ^ ((row & 7) << 4);
      gload_lds16((const char*)A  + ((size_t)(by * 128 + row) * K + k0) * 2 + csw,
                  (char*)sA + o);
      gload_lds16((const char*)Bw + ((size_t)(bx * 128 + row) * K + k0) * 2 + csw,
                  (char*)sB + o);
    }
  };

  STAGE(0);
  for (int kt = 0; kt < 16; ++kt) {
    __syncthreads();
    bf16x8 af[2][4], bfr[2][4];
    #pragma unroll
    for (int kk = 0; kk < 2; ++kk) {
      #pragma unroll
      for (int m = 0; m < 4; ++m) {
        const int row = wm * 64 + m * 16 + l15;
        const int col = (kk * 64 + l4 * 16) ^ ((row & 7) << 4);
        af[kk][m] = *(const bf16x8*)((const char*)sA + row * 128 + col);
      }
      #pragma unroll
      for (int n = 0; n < 4; ++n) {
        const int row = wn * 64 + n * 16 + l15;
        const int col = (kk * 64 + l4 * 16) ^ ((row & 7) << 4);
        bfr[kk][n] = *(const bf16x8*)((const char*)sB + row * 128 + col);
      }
    }
    __syncthreads();
    if (kt < 15) STAGE(kt + 1);
    __builtin_amdgcn_sched_barrier(0);
    #pragma unroll
    for (int kk = 0; kk < 2; ++kk)
      #pragma unroll
      for (int m = 0; m < 4; ++m)
        #pragma unroll
        for (int n = 0; n < 4; ++n)
          acc[m][n] = mfma_bf16(af[kk][m], bfr[kk][n], acc[m][n]);
  }
}

// XCD-aware remap (grid (8,32): x-major dispatch -> XCD = blockIdx.x)
__device__ __forceinline__ void xcd_remap(int& bx, int& by) {
  const int X = blockIdx.x, Y = blockIdx.y;
  by = X * 4 + (Y & 3);
  bx = Y >> 2;
}

// ---------- QKV projection GEMM + phi + LDS-repacked epilogue ----------
// grid (8, 32, 3): z = {q,k,v}.
// Outputs: z=0 q_phi (b,h,s,d); z=1 k_phi + kphiT (bh,c,d,s); z=2 vT.
__global__ __launch_bounds__(256, 3) void qkv_gemm(
    const hbf16* __restrict__ qin, const hbf16* __restrict__ kin, const hbf16* __restrict__ vin,
    const hbf16* __restrict__ wq, const hbf16* __restrict__ wk, const hbf16* __restrict__ wv,
    const float* __restrict__ bq, const float* __restrict__ bk, const float* __restrict__ bv,
    hbf16* __restrict__ q_phi, hbf16* __restrict__ k_phi,
    hbf16* __restrict__ kphiT, hbf16* __restrict__ vT)
{
  const int z = blockIdx.z;
  const hbf16* A    = (z == 0) ? qin : (z == 1) ? kin : vin;
  const hbf16* W    = (z == 0) ? wq  : (z == 1) ? wk  : wv;
  const float* bias = (z == 0) ? bq  : (z == 1) ? bk  : bv;

  int bx, by;
  xcd_remap(bx, by);

  __shared__ hbf16 smem[2 * 128 * 64];   // 32KB: sA | sB, reused by epilogue
  f32x4 acc[4][4] = {};
  gemm_core_128(A, W, by, bx, smem, smem + 128 * 64, acc);

  const int tid = threadIdx.x, lane = tid & 63, wid = tid >> 6;
  const int wm = wid >> 1, wn = wid & 1, l15 = lane & 15, l4 = lane >> 4;
  const int b = by >> 4;   // 128-row tile never crosses the batch boundary

  float bs[4];
  #pragma unroll
  for (int n = 0; n < 4; ++n) bs[n] = bias[bx * 128 + wn * 64 + n * 16 + l15];

  auto finish = [&](float v) -> float {
    return (z < 2) ? ((v > 0.f) ? (v + 1.f) : __expf(v)) : v;   // phi = elu+1
  };

  if (z < 2) {
    // ---- pass 1: normal (s, gn) layout ----
    #pragma unroll
    for (int n = 0; n < 4; ++n) {
      const int col = wn * 64 + n * 16 + l15;
      #pragma unroll
      for (int m = 0; m < 4; ++m) {
        #pragma unroll
        for (int j = 0; j < 4; ++j) {
          const int row = wm * 64 + m * 16 + l4 * 4 + j;
          smem[row * 128 + (col ^ ((row & 7) << 3))] =
              __float2bfloat16(finish(acc[m][n][j] + bs[n]));
        }
      }
    }
    __syncthreads();
    hbf16* dst = (z == 0) ? q_phi : k_phi;
    #pragma unroll
    for (int it = 0; it < 8; ++it) {
      const int sgi = it * 256 + tid;          // 0..2047
      const int sl = sgi >> 4, seg = sgi & 15;
      const uint4 vv = *(const uint4*)&smem[sl * 128 + ((seg * 8) ^ ((sl & 7) << 3))];
      const int gnb = bx * 128 + seg * 8;
      const int h = gnb >> 6, dd = gnb & 63;
      const int s = (by * 128 + sl) & 2047;
      *(uint4*)&dst[(((size_t)(b * 16 + h)) * 2048 + s) * 64 + dd] = vv;
    }
  }
  if (z >= 1) {
    if (z == 1) __syncthreads();               // LDS reuse between passes
    // ---- pass 2: transposed (gn, s) layout for kphiT / vT ----
    #pragma unroll
    for (int n = 0; n < 4; ++n) {
      const int gnl = wn * 64 + n * 16 + l15;
      const int x = (gnl & 7) << 3;
      #pragma unroll
      for (int m = 0; m < 4; ++m) {
        const int s0 = wm * 64 + m * 16 + l4 * 4;
        hbf16 pk[4];
        #pragma unroll
        for (int j = 0; j < 4; ++j)
          pk[j] = __float2bfloat16(finish(acc[m][n][j] + bs[n]));
        *(ushort4*)&smem[gnl * 128 + (s0 ^ x)] = *(ushort4*)pk;
      }
    }
    __syncthreads();
    hbf16* dst = (z == 1) ? kphiT : vT;
    #pragma unroll
    for (int it = 0; it < 8; ++it) {
      const int sgi = it * 256 + tid;          // 0..2047
      const int gn = sgi >> 4, sseg = sgi & 15;
      const uint4 vv = *(const uint4*)&smem[gn * 128 + ((sseg * 8) ^ ((gn & 7) << 3))];
      const int gnb = bx * 128 + gn;
      const int h = gnb >> 6, dd = gnb & 63;
      const int sg = by * 128 + sseg * 8;
      const int c = (sg & 2047) >> 6, sin = sg & 63;
      *(uint4*)&dst[(((size_t)(b * 16 + h)) * 32 + c) * 4096 + dd * 64 + sin] = vv;
    }
  }
}

// ---------- per-chunk KV^T_ext sums: [80][64] fp32 per (bh, chunk) ----------
__global__ __launch_bounds__(256) void chunk_sums(
    const hbf16* __restrict__ kphiT, const hbf16* __restrict__ vT,
    float* __restrict__ sums)
{
  const int c = blockIdx.x, bh = blockIdx.y;
  const int tid = threadIdx.x, lane = tid & 63, w = tid >> 6;
  const int l15 = lane & 15, l4 = lane >> 4;
  const size_t tbase = ((size_t)bh * 32 + c) * 4096;

  f32x4 acc[5] = {};
  #pragma unroll
  for (int kk = 0; kk < 2; ++kk) {
    const bf16x8 bfr = *(const bf16x8*)&kphiT[tbase + (w * 16 + l15) * 64 + l4 * 8 + kk * 32];
    #pragma unroll
    for (int mj = 0; mj < 5; ++mj) {
      bf16x8 af;
      if (mj < 4) {
        af = *(const bf16x8*)&vT[tbase + (mj * 16 + l15) * 64 + l4 * 8 + kk * 32];
      } else {
        const __bf16 e = (l15 == 0) ? (__bf16)1.0f : (__bf16)0.0f;
        #pragma unroll
        for (int i = 0; i < 8; ++i) af[i] = e;
      }
      acc[mj] = mfma_bf16(af, bfr, acc[mj]);
    }
  }
  float* outp = sums + ((size_t)bh * 32 + c) * 5120;
  #pragma unroll
  for (int mj = 0; mj < 5; ++mj) {
    #pragma unroll
    for (int j = 0; j < 4; ++j) {
      outp[(mj * 16 + l4 * 4 + j) * 64 + w * 16 + l15] = acc[mj][j];
    }
  }
}

// ---------- exclusive prefix scan over chunks, output bf16 ----------
__global__ __launch_bounds__(256) void chunk_scan(
    const float* __restrict__ sums, hbf16* __restrict__ pre)
{
  const int elem = blockIdx.x * 256 + threadIdx.x;   // 0..5119
  const int bh = blockIdx.y;
  const size_t base = (size_t)bh * 32 * 5120 + elem;
  float v[32];
  #pragma unroll
  for (int c = 0; c < 32; ++c) v[c] = sums[base + (size_t)c * 5120];
  float run = 0.f;
  #pragma unroll
  for (int c = 0; c < 32; ++c) {
    pre[base + (size_t)c * 5120] = __float2bfloat16(run);
    run += v[c];
  }
}

// ---------- per-chunk attention: intra (masked) + inter (prefix) ----------
__global__ __launch_bounds__(256) void attn_chunk(
    const hbf16* __restrict__ q_phi, const hbf16* __restrict__ k_phi,
    const hbf16* __restrict__ vT, const hbf16* __restrict__ pre,
    hbf16* __restrict__ attn)
{
  const int c = blockIdx.x, bh = blockIdx.y;
  const int tid = threadIdx.x, lane = tid & 63, w = tid >> 6;
  const int l15 = lane & 15, l4 = lane >> 4;
  __shared__ hbf16 sS[4 * 16 * 64];   // scores, then reused as 64x64 out tile

  const size_t qbase = ((size_t)bh * 2048 + c * 64) * 64;
  const size_t tbase = ((size_t)bh * 32 + c) * 4096;
  const size_t pbase = ((size_t)bh * 32 + c) * 5120;

  bf16x8 aq[2];
  #pragma unroll
  for (int kk = 0; kk < 2; ++kk)
    aq[kk] = *(const bf16x8*)&q_phi[qbase + (w * 16 + l15) * 64 + l4 * 8 + kk * 32];

  f32x4 accS[4] = {};
  #pragma unroll
  for (int kk = 0; kk < 2; ++kk) {
    #pragma unroll
    for (int ni = 0; ni < 4; ++ni) {
      const bf16x8 bk = *(const bf16x8*)&k_phi[qbase + (ni * 16 + l15) * 64 + l4 * 8 + kk * 32];
      accS[ni] = mfma_bf16(aq[kk], bk, accS[ni]);
    }
  }
  #pragma unroll
  for (int ni = 0; ni < 4; ++ni) {
    #pragma unroll
    for (int j = 0; j < 4; ++j) {
      const int r  = l4 * 4 + j;
      const int cc = ni * 16 + l15;
      const float v = (cc <= w * 16 + r) ? accS[ni][j] : 0.f;
      sS[w * 1024 + r * 64 + (cc ^ ((r & 7) << 3))] = __float2bfloat16(v);
    }
  }
  // (wave-local LDS use: no barrier needed)

  f32x4 accN[5] = {};
  #pragma unroll
  for (int kk = 0; kk < 2; ++kk) {
    const bf16x8 aS = *(const bf16x8*)&sS[w * 1024 + l15 * 64 +
                                          ((l4 * 8 + kk * 32) ^ ((l15 & 7) << 3))];
    #pragma unroll
    for (int ni = 0; ni < 5; ++ni) {
      bf16x8 bv;
      if (ni < 4) {
        bv = *(const bf16x8*)&vT[tbase + (ni * 16 + l15) * 64 + l4 * 8 + kk * 32];
      } else {
        const __bf16 e = (l15 == 0) ? (__bf16)1.0f : (__bf16)0.0f;
        #pragma unroll
        for (int i = 0; i < 8; ++i) bv[i] = e;
      }
      accN[ni] = mfma_bf16(aS, bv, accN[ni]);
    }
  }
  #pragma unroll
  for (int kk = 0; kk < 2; ++kk) {
    #pragma unroll
    for (int ni = 0; ni < 5; ++ni) {
      const bf16x8 bp = *(const bf16x8*)&pre[pbase + (ni * 16 + l15) * 64 + l4 * 8 + kk * 32];
      accN[ni] = mfma_bf16(aq[kk], bp, accN[ni]);
    }
  }
  // divide + LDS repack + coalesced dump
  const int b = bh >> 4, h = bh & 15;
  #pragma unroll
  for (int j = 0; j < 4; ++j) {
    const float den = __shfl(accN[4][j], lane & 48);
    const float inv = 1.f / (den + 1e-6f);
    const int sl = w * 16 + l4 * 4 + j;
    #pragma unroll
    for (int ni = 0; ni < 4; ++ni) {
      sS[sl * 64 + ((ni * 16 + l15) ^ ((sl & 7) << 3))] =
          __float2bfloat16(accN[ni][j] * inv);
    }
  }
  __syncthreads();
  #pragma unroll
  for (int it = 0; it < 2; ++it) {
    const int sgi = it * 256 + tid;            // 0..511
    const int sl = sgi >> 3, seg = sgi & 7;
    const uint4 vv = *(const uint4*)&sS[sl * 64 + ((seg * 8) ^ ((sl & 7) << 3))];
    *(uint4*)&attn[((size_t)b * 2048 + c * 64 + sl) * 1024 + h * 64 + seg * 8] = vv;
  }
}

// ---------- output projection GEMM: 64x128 2-phase core, 512 blocks ----------
__global__ __launch_bounds__(256, 3) void out_gemm(
    const hbf16* __restrict__ attn, const hbf16* __restrict__ wo,
    const float* __restrict__ bo, float* __restrict__ out)
{
  // grid (8, 64): x-major dispatch -> XCD = blockIdx.x (512 % 8 == 0).
  const int X = blockIdx.x, Y = blockIdx.y;
  const int by = X * 8 + (Y & 7);   // 0..63
  const int bx = Y >> 3;            // 0..7

  __shared__ hbf16 sA[64 * 64];     // 8KB
  __shared__ hbf16 sB[128 * 64];    // 16KB
  const int tid  = threadIdx.x;
  const int lane = tid & 63;
  const int wid  = tid >> 6;
  const int l15 = lane & 15, l4 = lane >> 4;
  const int K = 1024;

  auto STAGE = [&](int kt) {
    const int k0 = kt * 64;
    #pragma unroll
    for (int j = 0; j < 2; ++j) {               // A tile 64x64
      const int o   = (j * 256 + tid) * 16;
      const int row = o >> 7;
      const int csw = (o & 127) ^ ((row & 7) << 4);
      gload_lds16((const char*)attn + ((size_t)(by * 64 + row) * K + k0) * 2 + csw,
                  (char*)sA + o);
    }
    #pragma unroll
    for (int j = 0; j < 4; ++j) {               // B tile 128x64
      const int o   = (j * 256 + tid) * 16;
      const int row = o >> 7;
      const int csw = (o & 127) ^ ((row & 7) << 4);
      gload_lds16((const char*)wo + ((size_t)(bx * 128 + row) * K + k0) * 2 + csw,
                  (char*)sB + o);
    }
  };

  f32x4 acc[4][2] = {};
  STAGE(0);
  for (int kt = 0; kt < 16; ++kt) {
    __syncthreads();
    bf16x8 af[2][4], bfr[2][2];
    #pragma unroll
    for (int kk = 0; kk < 2; ++kk) {
      #pragma unroll
      for (int m = 0; m < 4; ++m) {
        const int row = m * 16 + l15;
        const int col = (kk * 64 + l4 * 16) ^ ((row & 7) << 4);
        af[kk][m] = *(const bf16x8*)((const char*)sA + row * 128 + col);
      }
      #pragma unroll
      for (int n = 0; n < 2; ++n) {
        const int row = wid * 32 + n * 16 + l15;
        const int col = (kk * 64 + l4 * 16) ^ ((row & 7) << 4);
        bfr[kk][n] = *(const bf16x8*)((const char*)sB + row * 128 + col);
      }
    }
    __syncthreads();
    if (kt < 15) STAGE(kt + 1);
    __builtin_amdgcn_sched_barrier(0);
    #pragma unroll
    for (int kk = 0; kk < 2; ++kk)
      #pragma unroll
      for (int m = 0; m < 4; ++m)
        #pragma unroll
        for (int n = 0; n < 2; ++n)
          acc[m][n] = mfma_bf16(af[kk][m], bfr[kk][n], acc[m][n]);
  }

  #pragma unroll
  for (int n = 0; n < 2; ++n) {
    const int gn = bx * 128 + wid * 32 + n * 16 + l15;
    const float bs = bo[gn];
    #pragma unroll
    for (int m = 0; m < 4; ++m) {
      #pragma unroll
      for (int j = 0; j < 4; ++j) {
        const int gm = by * 64 + m * 16 + l4 * 4 + j;
        out[(size_t)gm * 1024 + gn] = acc[m][n][j] + bs;   // fp32, 64B lines
      }
    }
  }
}

// ---------- launch ----------
extern "C" void kernel_launch(void* const* d_in, const int* in_sizes, int n_in,
                              void* d_out, int out_size, void* d_ws, size_t ws_size,
                              hipStream_t stream) {
  const float* q  = (const float*)d_in[0];
  const float* k  = (const float*)d_in[1];
  const float* v  = (const float*)d_in[2];
  const float* Wq = (const float*)d_in[3];
  const float* bq = (const float*)d_in[4];
  const float* Wk = (const float*)d_in[5];
  const float* bk = (const float*)d_in[6];
  const float* Wv = (const float*)d_in[7];
  const float* bv = (const float*)d_in[8];
  const float* Wo = (const float*)d_in[9];
  const float* bo = (const float*)d_in[10];

  char* ws = (char*)d_ws;
  const size_t MB = (size_t)1 << 20;
  hbf16* qin  = (hbf16*)(ws + 0 * MB);
  hbf16* kin  = (hbf16*)(ws + 8 * MB);
  hbf16* vin  = (hbf16*)(ws + 16 * MB);
  hbf16* wqb  = (hbf16*)(ws + 24 * MB);
  hbf16* wkb  = (hbf16*)(ws + 26 * MB);
  hbf16* wvb  = (hbf16*)(ws + 28 * MB);
  hbf16* wob  = (hbf16*)(ws + 30 * MB);
  hbf16* qphi = (hbf16*)(ws + 32 * MB);
  hbf16* kphi = (hbf16*)(ws + 40 * MB);
  hbf16* kphT = (hbf16*)(ws + 48 * MB);
  hbf16* vTb  = (hbf16*)(ws + 56 * MB);
  hbf16* attn = (hbf16*)(ws + 64 * MB);
  float* sums = (float*)(ws + 72 * MB);   // 20 MiB
  hbf16* pre  = (hbf16*)(ws + 92 * MB);

  convert_all<<<8192, 256, 0, stream>>>(q, k, v, Wq, Wk, Wv, Wo, qin);
  qkv_gemm<<<dim3(8, 32, 3), 256, 0, stream>>>(qin, kin, vin, wqb, wkb, wvb,
                                               bq, bk, bv, qphi, kphi, kphT, vTb);
  chunk_sums<<<dim3(32, 32), 256, 0, stream>>>(kphT, vTb, sums);
  chunk_scan<<<dim3(20, 32), 256, 0, stream>>>(sums, pre);
  attn_chunk<<<dim3(32, 32), 256, 0, stream>>>(qphi, kphi, vTb, pre, attn);
  out_gemm<<<dim3(8, 64), 256, 0, stream>>>(attn, wob, bo, (float*)d_out);
}